// Round 1
// baseline (528.684 us; speedup 1.0000x reference)
//
#include <hip/hip_runtime.h>
#include <hip/hip_bf16.h>

constexpr int IN_DIM = 128;
constexpr int HID    = 256;

// ---------------- setup kernels ----------------

__global__ void zero_int2(int* __restrict__ a, int* __restrict__ b, int n) {
    int i = blockIdx.x * blockDim.x + threadIdx.x;
    if (i < n) { a[i] = 0; b[i] = 0; }
}

__global__ void count_deg(const int* __restrict__ dst, int* __restrict__ deg, int e) {
    int i = blockIdx.x * blockDim.x + threadIdx.x;
    if (i < e) atomicAdd(&deg[dst[i]], 1);
}

__global__ void compute_dinv(const int* __restrict__ deg, float* __restrict__ dinv, int n) {
    int i = blockIdx.x * blockDim.x + threadIdx.x;
    if (i < n) dinv[i] = rsqrtf((float)deg[i] + 1.0f);
}

// exclusive prefix sum of deg[0..n) -> rowptr[0..n], single block of 1024
__global__ __launch_bounds__(1024) void scan_deg(const int* __restrict__ deg,
                                                 int* __restrict__ rowptr, int n) {
    __shared__ int sums[1024];
    int t = threadIdx.x;
    int chunk = (n + 1023) >> 10;
    int start = t * chunk;
    int end   = min(start + chunk, n);
    int s = 0;
    for (int i = start; i < end; i++) s += deg[i];
    sums[t] = s;
    __syncthreads();
    for (int off = 1; off < 1024; off <<= 1) {
        int v = sums[t];
        int w = (t >= off) ? sums[t - off] : 0;
        __syncthreads();
        sums[t] = v + w;
        __syncthreads();
    }
    int base = (t > 0) ? sums[t - 1] : 0;
    for (int i = start; i < end; i++) { rowptr[i] = base; base += deg[i]; }
    if (t == 0) rowptr[n] = sums[1023];
}

__global__ void scatter_edges(const int* __restrict__ src, const int* __restrict__ dst,
                              const int* __restrict__ rowptr, int* __restrict__ cursor,
                              int* __restrict__ ssrc, int e) {
    int i = blockIdx.x * blockDim.x + threadIdx.x;
    if (i < e) {
        int d = dst[i];
        int p = atomicAdd(&cursor[d], 1);
        ssrc[rowptr[d] + p] = src[i];
    }
}

// ---------------- aggregation: one wave per node ----------------
// out[i] = sum_{s in nbrs(i)} dinv[s]*dinv[i]*h[s] + dinv[i]^2 * h[i]
template <int V>  // V floats per lane; F = 64*V features
__global__ __launch_bounds__(256) void aggregate(const float* __restrict__ h,
                                                 const int* __restrict__ rowptr,
                                                 const int* __restrict__ ssrc,
                                                 const float* __restrict__ dinv,
                                                 float* __restrict__ out, int n) {
    int wid  = (blockIdx.x * 256 + threadIdx.x) >> 6;
    int lane = threadIdx.x & 63;
    if (wid >= n) return;
    constexpr int F = V * 64;
    float di = dinv[wid];
    float sw = di * di;
    float acc[V];
    {
        const float* row = h + (size_t)wid * F + lane * V;
        if constexpr (V == 4) {
            float4 v = *(const float4*)row;
            acc[0] = v.x * sw; acc[1] = v.y * sw; acc[2] = v.z * sw; acc[3] = v.w * sw;
        } else {
            float2 v = *(const float2*)row;
            acc[0] = v.x * sw; acc[1] = v.y * sw;
        }
    }
    int beg = rowptr[wid], fin = rowptr[wid + 1];
    for (int j = beg; j < fin; j++) {
        int s = ssrc[j];
        float w = dinv[s] * di;
        const float* r = h + (size_t)s * F + lane * V;
        if constexpr (V == 4) {
            float4 v = *(const float4*)r;
            acc[0] += v.x * w; acc[1] += v.y * w; acc[2] += v.z * w; acc[3] += v.w * w;
        } else {
            float2 v = *(const float2*)r;
            acc[0] += v.x * w; acc[1] += v.y * w;
        }
    }
    float* o = out + (size_t)wid * F + lane * V;
    if constexpr (V == 4) *(float4*)o = make_float4(acc[0], acc[1], acc[2], acc[3]);
    else                  *(float2*)o = make_float2(acc[0], acc[1]);
}

// ---------------- fp32 tiled GEMM + bias + relu ----------------
// C[M,256] = relu(A[M,K] @ B[K,256] + bias)
template <int K>
__global__ __launch_bounds__(256) void gemm_bias_relu(const float* __restrict__ A,
                                                      const float* __restrict__ B,
                                                      const float* __restrict__ bias,
                                                      float* __restrict__ C, int M) {
    constexpr int BK = 16;
    __shared__ float As[BK][64];
    __shared__ float Bs[BK][64];
    int tid = threadIdx.x;
    int tx = tid & 15;   // 16 col-groups of 4
    int ty = tid >> 4;   // 16 row-groups of 4
    int row0 = blockIdx.x * 64;
    int col0 = blockIdx.y * 64;

    int arow = tid >> 2;          // 0..63
    int acol = (tid & 3) * 4;     // 0,4,8,12
    int brow = tid >> 4;          // 0..15
    int bcol = (tid & 15) * 4;    // 0..60

    float acc[4][4] = {};
    for (int k0 = 0; k0 < K; k0 += BK) {
        int gr = row0 + arow;
        float4 av = make_float4(0.f, 0.f, 0.f, 0.f);
        if (gr < M) av = *(const float4*)(A + (size_t)gr * K + k0 + acol);
        As[acol + 0][arow] = av.x;
        As[acol + 1][arow] = av.y;
        As[acol + 2][arow] = av.z;
        As[acol + 3][arow] = av.w;
        float4 bv = *(const float4*)(B + (size_t)(k0 + brow) * 256 + col0 + bcol);
        *(float4*)&Bs[brow][bcol] = bv;
        __syncthreads();
#pragma unroll
        for (int k = 0; k < BK; k++) {
            float4 a = *(const float4*)&As[k][ty * 4];
            float4 b = *(const float4*)&Bs[k][tx * 4];
            float ar[4] = {a.x, a.y, a.z, a.w};
            float br[4] = {b.x, b.y, b.z, b.w};
#pragma unroll
            for (int i = 0; i < 4; i++)
#pragma unroll
                for (int j = 0; j < 4; j++) acc[i][j] += ar[i] * br[j];
        }
        __syncthreads();
    }
#pragma unroll
    for (int i = 0; i < 4; i++) {
        int r = row0 + ty * 4 + i;
        if (r < M) {
            int c = col0 + tx * 4;
            float4 o;
            o.x = fmaxf(acc[i][0] + bias[c + 0], 0.f);
            o.y = fmaxf(acc[i][1] + bias[c + 1], 0.f);
            o.z = fmaxf(acc[i][2] + bias[c + 2], 0.f);
            o.w = fmaxf(acc[i][3] + bias[c + 3], 0.f);
            *(float4*)(C + (size_t)r * 256 + c) = o;
        }
    }
}

// ---------------- final projection: out[n,2] = h2 @ Wl + bl ----------------
__global__ __launch_bounds__(256) void final_gemm(const float* __restrict__ h2,
                                                  const float* __restrict__ Wl,
                                                  const float* __restrict__ bl,
                                                  float* __restrict__ out, int n) {
    int wid  = (blockIdx.x * 256 + threadIdx.x) >> 6;
    int lane = threadIdx.x & 63;
    if (wid >= n) return;
    float4 h = *(const float4*)(h2 + (size_t)wid * HID + lane * 4);
    const float4* wl4 = (const float4*)(Wl + lane * 8);  // rows lane*4..lane*4+3, 2 cols
    float4 w0 = wl4[0];  // (W[r0][0],W[r0][1],W[r1][0],W[r1][1])
    float4 w1 = wl4[1];
    float p0 = h.x * w0.x + h.y * w0.z + h.z * w1.x + h.w * w1.z;
    float p1 = h.x * w0.y + h.y * w0.w + h.z * w1.y + h.w * w1.w;
    for (int off = 32; off; off >>= 1) {
        p0 += __shfl_down(p0, off);
        p1 += __shfl_down(p1, off);
    }
    if (lane == 0) {
        out[(size_t)wid * 2 + 0] = p0 + bl[0];
        out[(size_t)wid * 2 + 1] = p1 + bl[1];
    }
}

// ---------------- launch ----------------

extern "C" void kernel_launch(void* const* d_in, const int* in_sizes, int n_in,
                              void* d_out, int out_size, void* d_ws, size_t ws_size,
                              hipStream_t stream) {
    const float* x  = (const float*)d_in[0];
    const int*   ei = (const int*)d_in[1];
    const float* W1 = (const float*)d_in[2];
    const float* b1 = (const float*)d_in[3];
    const float* W2 = (const float*)d_in[4];
    const float* b2 = (const float*)d_in[5];
    const float* Wl = (const float*)d_in[6];
    const float* bl = (const float*)d_in[7];
    float* out = (float*)d_out;

    int n = in_sizes[0] / IN_DIM;  // 50000
    int e = in_sizes[1] / 2;       // 600000
    const int* src = ei;
    const int* dst = ei + e;

    char* ws = (char*)d_ws;
    size_t off = 0;
    auto alloc = [&](size_t bytes) -> void* {
        void* p = ws + off;
        off += (bytes + 255) & ~(size_t)255;
        return p;
    };
    int*   deg    = (int*)alloc((size_t)n * 4);
    int*   cursor = (int*)alloc((size_t)n * 4);
    float* dinv   = (float*)alloc((size_t)n * 4);
    int*   rowptr = (int*)alloc((size_t)(n + 1) * 4);
    int*   ssrc   = (int*)alloc((size_t)e * 4);
    float* aggx   = (float*)alloc((size_t)n * IN_DIM * 4);
    float* h1     = (float*)alloc((size_t)n * HID * 4);
    float* aggh   = (float*)alloc((size_t)n * HID * 4);
    float* h2     = h1;  // h1 dead after aggregate<4>; reuse for h2

    int nb = (n + 255) / 256;
    int eb = (e + 255) / 256;

    zero_int2<<<nb, 256, 0, stream>>>(deg, cursor, n);
    count_deg<<<eb, 256, 0, stream>>>(dst, deg, e);
    compute_dinv<<<nb, 256, 0, stream>>>(deg, dinv, n);
    scan_deg<<<1, 1024, 0, stream>>>(deg, rowptr, n);
    scatter_edges<<<eb, 256, 0, stream>>>(src, dst, rowptr, cursor, ssrc, e);

    // layer 1: aggregate x (128 features) first, then GEMM (+b1, relu)
    aggregate<2><<<(n + 3) / 4, 256, 0, stream>>>(x, rowptr, ssrc, dinv, aggx, n);
    dim3 g1((n + 63) / 64, 4);
    gemm_bias_relu<128><<<g1, 256, 0, stream>>>(aggx, W1, b1, h1, n);

    // layer 2: aggregate h1 (256 features), then GEMM (+b2, relu)
    aggregate<4><<<(n + 3) / 4, 256, 0, stream>>>(h1, rowptr, ssrc, dinv, aggh, n);
    gemm_bias_relu<256><<<g1, 256, 0, stream>>>(aggh, W2, b2, h2, n);

    // final projection 256 -> 2
    final_gemm<<<(n + 3) / 4, 256, 0, stream>>>(h2, Wl, bl, out, n);
}

// Round 2
// 440.251 us; speedup vs baseline: 1.2009x; 1.2009x over previous
//
#include <hip/hip_runtime.h>
#include <hip/hip_bf16.h>

constexpr int IN_DIM = 128;
constexpr int HID    = 256;

typedef short  bf16x8 __attribute__((ext_vector_type(8)));
typedef ushort u16x8  __attribute__((ext_vector_type(8)));
typedef float  f32x4  __attribute__((ext_vector_type(4)));

__device__ inline ushort bf16_rn(float x) {
    uint u = __float_as_uint(x);
    uint r = u + 0x7FFFu + ((u >> 16) & 1u);
    return (ushort)(r >> 16);
}
__device__ inline void split_bf16(float x, ushort& hi, ushort& lo) {
    ushort h = bf16_rn(x);
    float hf = __uint_as_float(((uint)h) << 16);
    hi = h;
    lo = bf16_rn(x - hf);
}

// ---------------- setup kernels ----------------

__global__ void zero_int2(int* __restrict__ a, int* __restrict__ b, int n) {
    int i = blockIdx.x * blockDim.x + threadIdx.x;
    if (i < n) { a[i] = 0; b[i] = 0; }
}

__global__ void count_deg(const int* __restrict__ dst, int* __restrict__ deg, int e) {
    int i = blockIdx.x * blockDim.x + threadIdx.x;
    if (i < e) atomicAdd(&deg[dst[i]], 1);
}

__global__ void compute_dinv(const int* __restrict__ deg, float* __restrict__ dinv, int n) {
    int i = blockIdx.x * blockDim.x + threadIdx.x;
    if (i < n) dinv[i] = rsqrtf((float)deg[i] + 1.0f);
}

__global__ __launch_bounds__(1024) void scan_deg(const int* __restrict__ deg,
                                                 int* __restrict__ rowptr, int n) {
    __shared__ int sums[1024];
    int t = threadIdx.x;
    int chunk = (n + 1023) >> 10;
    int start = t * chunk;
    int end   = min(start + chunk, n);
    int s = 0;
    for (int i = start; i < end; i++) s += deg[i];
    sums[t] = s;
    __syncthreads();
    for (int off = 1; off < 1024; off <<= 1) {
        int v = sums[t];
        int w = (t >= off) ? sums[t - off] : 0;
        __syncthreads();
        sums[t] = v + w;
        __syncthreads();
    }
    int base = (t > 0) ? sums[t - 1] : 0;
    for (int i = start; i < end; i++) { rowptr[i] = base; base += deg[i]; }
    if (t == 0) rowptr[n] = sums[1023];
}

__global__ void scatter_edges(const int* __restrict__ src, const int* __restrict__ dst,
                              const int* __restrict__ rowptr, int* __restrict__ cursor,
                              int* __restrict__ ssrc, int e) {
    int i = blockIdx.x * blockDim.x + threadIdx.x;
    if (i < e) {
        int d = dst[i];
        int p = atomicAdd(&cursor[d], 1);
        ssrc[rowptr[d] + p] = src[i];
    }
}

// ---------------- weight preconvert: B[K][256] fp32 -> hi/lo bf16 panels ----
// layout: [k>>5][n][k&31] (ushort), panel stride 256*32
template <int K>
__global__ void convert_B(const float* __restrict__ B, ushort* __restrict__ Bh,
                          ushort* __restrict__ Bl) {
    int id = blockIdx.x * 256 + threadIdx.x;
    if (id >= K * 64) return;
    int k  = id >> 6;
    int n4 = (id & 63) * 4;
    float4 v = *(const float4*)(B + (size_t)k * 256 + n4);
    size_t base = (size_t)(k >> 5) * (256 * 32) + (k & 31);
    float vv[4] = {v.x, v.y, v.z, v.w};
#pragma unroll
    for (int c = 0; c < 4; c++) {
        ushort h, l;
        split_bf16(vv[c], h, l);
        Bh[base + (size_t)(n4 + c) * 32] = h;
        Bl[base + (size_t)(n4 + c) * 32] = l;
    }
}

// ---------------- aggregation: one wave per node ----------------
template <int V>
__global__ __launch_bounds__(256) void aggregate(const float* __restrict__ h,
                                                 const int* __restrict__ rowptr,
                                                 const int* __restrict__ ssrc,
                                                 const float* __restrict__ dinv,
                                                 float* __restrict__ out, int n) {
    int wid  = (blockIdx.x * 256 + threadIdx.x) >> 6;
    int lane = threadIdx.x & 63;
    if (wid >= n) return;
    constexpr int F = V * 64;
    float di = dinv[wid];
    float sw = di * di;
    float acc[V];
    {
        const float* row = h + (size_t)wid * F + lane * V;
        if constexpr (V == 4) {
            float4 v = *(const float4*)row;
            acc[0] = v.x * sw; acc[1] = v.y * sw; acc[2] = v.z * sw; acc[3] = v.w * sw;
        } else {
            float2 v = *(const float2*)row;
            acc[0] = v.x * sw; acc[1] = v.y * sw;
        }
    }
    int beg = rowptr[wid], fin = rowptr[wid + 1];
    for (int j = beg; j < fin; j++) {
        int s = ssrc[j];
        float w = dinv[s] * di;
        const float* r = h + (size_t)s * F + lane * V;
        if constexpr (V == 4) {
            float4 v = *(const float4*)r;
            acc[0] += v.x * w; acc[1] += v.y * w; acc[2] += v.z * w; acc[3] += v.w * w;
        } else {
            float2 v = *(const float2*)r;
            acc[0] += v.x * w; acc[1] += v.y * w;
        }
    }
    float* o = out + (size_t)wid * F + lane * V;
    if constexpr (V == 4) *(float4*)o = make_float4(acc[0], acc[1], acc[2], acc[3]);
    else                  *(float2*)o = make_float2(acc[0], acc[1]);
}

// ---------------- MFMA split-bf16 GEMM ----------------
// C[M,256] = relu(A[M,K] @ B[K,256] + bias); optionally fused out = C @ Wl + bl
// A fp32 row-major; B pre-split into hi/lo bf16 panels [K/32][256][32].
// Block: 256 thr = 4 waves; BM=64, BN=256 (wave w owns cols [64w,64w+64)), BK=32.
template <int K, bool FUSE_FINAL>
__global__ __launch_bounds__(256, 3) void gemm_mfma(const float* __restrict__ A,
                                                    const ushort* __restrict__ Bh,
                                                    const ushort* __restrict__ Bl,
                                                    const float* __restrict__ bias,
                                                    float* __restrict__ C,
                                                    const float* __restrict__ Wl,
                                                    const float* __restrict__ bl,
                                                    float* __restrict__ out, int M) {
    // pad rows to 40 ushorts (80B): 16B-aligned b128, 8 consecutive rows tile all banks
    __shared__ ushort Ah[64][40], Al[64][40];
    __shared__ ushort Bsh[256][40], Bsl[256][40];
    __shared__ float part[4][64][2];

    int tid  = threadIdx.x;
    int w    = tid >> 6;
    int lane = tid & 63;
    int l15  = lane & 15;
    int quad = lane >> 4;
    int row0 = blockIdx.x * 64;

    // A staging assignment: thread -> row=tid>>2 (0..63), k-offset=(tid&3)*8
    int arow = tid >> 2;
    int ak   = (tid & 3) * 8;
    int gr   = row0 + arow;
    bool arow_ok = (gr < M);
    const float* aptr = A + (size_t)gr * K + ak;

    f32x4 acc[4][4] = {};

    for (int k0 = 0; k0 < K; k0 += 32) {
        // global loads first (no LDS touch)
        float av[8];
        if (arow_ok) {
            float4 v0 = *(const float4*)(aptr + k0);
            float4 v1 = *(const float4*)(aptr + k0 + 4);
            av[0]=v0.x; av[1]=v0.y; av[2]=v0.z; av[3]=v0.w;
            av[4]=v1.x; av[5]=v1.y; av[6]=v1.z; av[7]=v1.w;
        } else {
#pragma unroll
            for (int c = 0; c < 8; c++) av[c] = 0.f;
        }
        size_t panel = (size_t)(k0 >> 5) * (256 * 32) + (size_t)tid * 32;
        const uint4* bhsrc = (const uint4*)(Bh + panel);
        const uint4* blsrc = (const uint4*)(Bl + panel);
        uint4 bh0 = bhsrc[0], bh1 = bhsrc[1], bh2 = bhsrc[2], bh3 = bhsrc[3];
        uint4 bl0 = blsrc[0], bl1 = blsrc[1], bl2 = blsrc[2], bl3 = blsrc[3];

        __syncthreads();  // previous chunk's fragment reads done

        u16x8 hv, lv;
#pragma unroll
        for (int c = 0; c < 8; c++) {
            ushort h, l;
            split_bf16(av[c], h, l);
            hv[c] = h; lv[c] = l;
        }
        *(u16x8*)&Ah[arow][ak] = hv;
        *(u16x8*)&Al[arow][ak] = lv;
        {
            uint4* d0 = (uint4*)&Bsh[tid][0];
            d0[0]=bh0; d0[1]=bh1; d0[2]=bh2; d0[3]=bh3;
            uint4* d1 = (uint4*)&Bsl[tid][0];
            d1[0]=bl0; d1[1]=bl1; d1[2]=bl2; d1[3]=bl3;
        }
        __syncthreads();

        bf16x8 af_h[4], af_l[4], bf_h[4], bf_l[4];
#pragma unroll
        for (int i = 0; i < 4; i++) {
            af_h[i] = *(const bf16x8*)&Ah[i * 16 + l15][quad * 8];
            af_l[i] = *(const bf16x8*)&Al[i * 16 + l15][quad * 8];
        }
#pragma unroll
        for (int j = 0; j < 4; j++) {
            int n = w * 64 + j * 16 + l15;
            bf_h[j] = *(const bf16x8*)&Bsh[n][quad * 8];
            bf_l[j] = *(const bf16x8*)&Bsl[n][quad * 8];
        }
#pragma unroll
        for (int i = 0; i < 4; i++)
#pragma unroll
            for (int j = 0; j < 4; j++) {
                acc[i][j] = __builtin_amdgcn_mfma_f32_16x16x32_bf16(af_h[i], bf_h[j], acc[i][j], 0, 0, 0);
                acc[i][j] = __builtin_amdgcn_mfma_f32_16x16x32_bf16(af_h[i], bf_l[j], acc[i][j], 0, 0, 0);
                acc[i][j] = __builtin_amdgcn_mfma_f32_16x16x32_bf16(af_l[i], bf_h[j], acc[i][j], 0, 0, 0);
            }
    }

    // bias per col-tile
    float bj[4];
#pragma unroll
    for (int j = 0; j < 4; j++) bj[j] = bias[w * 64 + j * 16 + l15];

    if constexpr (!FUSE_FINAL) {
        // store relu(acc + bias) to C
#pragma unroll
        for (int i = 0; i < 4; i++)
#pragma unroll
            for (int reg = 0; reg < 4; reg++) {
                int r = row0 + i * 16 + quad * 4 + reg;
                if (r < M) {
                    float* cp = C + (size_t)r * 256 + w * 64 + l15;
#pragma unroll
                    for (int j = 0; j < 4; j++)
                        cp[j * 16] = fmaxf(acc[i][j][reg] + bj[j], 0.f);
                }
            }
    } else {
        float wl0[4], wl1[4];
#pragma unroll
        for (int j = 0; j < 4; j++) {
            int cj = w * 64 + j * 16 + l15;
            float2 wv = *(const float2*)(Wl + cj * 2);
            wl0[j] = wv.x; wl1[j] = wv.y;
        }
#pragma unroll
        for (int i = 0; i < 4; i++)
#pragma unroll
            for (int reg = 0; reg < 4; reg++) {
                float s0 = 0.f, s1 = 0.f;
#pragma unroll
                for (int j = 0; j < 4; j++) {
                    float v = fmaxf(acc[i][j][reg] + bj[j], 0.f);
                    s0 += v * wl0[j];
                    s1 += v * wl1[j];
                }
#pragma unroll
                for (int off = 1; off < 16; off <<= 1) {
                    s0 += __shfl_xor(s0, off);
                    s1 += __shfl_xor(s1, off);
                }
                if (l15 == 0) {
                    int r = i * 16 + quad * 4 + reg;
                    part[w][r][0] = s0;
                    part[w][r][1] = s1;
                }
            }
        __syncthreads();
        if (tid < 128) {
            int r = tid >> 1, o = tid & 1;
            int grr = row0 + r;
            if (grr < M) {
                float s = part[0][r][o] + part[1][r][o] + part[2][r][o] + part[3][r][o] + bl[o];
                out[(size_t)grr * 2 + o] = s;
            }
        }
    }
}

// ---------------- launch ----------------

extern "C" void kernel_launch(void* const* d_in, const int* in_sizes, int n_in,
                              void* d_out, int out_size, void* d_ws, size_t ws_size,
                              hipStream_t stream) {
    const float* x  = (const float*)d_in[0];
    const int*   ei = (const int*)d_in[1];
    const float* W1 = (const float*)d_in[2];
    const float* b1 = (const float*)d_in[3];
    const float* W2 = (const float*)d_in[4];
    const float* b2 = (const float*)d_in[5];
    const float* Wl = (const float*)d_in[6];
    const float* bl = (const float*)d_in[7];
    float* out = (float*)d_out;

    int n = in_sizes[0] / IN_DIM;  // 50000
    int e = in_sizes[1] / 2;       // 600000
    const int* src = ei;
    const int* dst = ei + e;

    char* ws = (char*)d_ws;
    size_t off = 0;
    auto alloc = [&](size_t bytes) -> void* {
        void* p = ws + off;
        off += (bytes + 255) & ~(size_t)255;
        return p;
    };
    int*    deg    = (int*)alloc((size_t)n * 4);
    int*    cursor = (int*)alloc((size_t)n * 4);
    float*  dinv   = (float*)alloc((size_t)n * 4);
    int*    rowptr = (int*)alloc((size_t)(n + 1) * 4);
    int*    ssrc   = (int*)alloc((size_t)e * 4);
    float*  aggx   = (float*)alloc((size_t)n * IN_DIM * 4);
    float*  h1     = (float*)alloc((size_t)n * HID * 4);
    float*  aggh   = (float*)alloc((size_t)n * HID * 4);
    ushort* B1h    = (ushort*)alloc((size_t)IN_DIM * 256 * 2);
    ushort* B1l    = (ushort*)alloc((size_t)IN_DIM * 256 * 2);
    ushort* B2h    = (ushort*)alloc((size_t)HID * 256 * 2);
    ushort* B2l    = (ushort*)alloc((size_t)HID * 256 * 2);

    int nb = (n + 255) / 256;
    int eb = (e + 255) / 256;

    zero_int2<<<nb, 256, 0, stream>>>(deg, cursor, n);
    count_deg<<<eb, 256, 0, stream>>>(dst, deg, e);
    compute_dinv<<<nb, 256, 0, stream>>>(deg, dinv, n);
    scan_deg<<<1, 1024, 0, stream>>>(deg, rowptr, n);
    scatter_edges<<<eb, 256, 0, stream>>>(src, dst, rowptr, cursor, ssrc, e);

    convert_B<IN_DIM><<<IN_DIM * 64 / 256, 256, 0, stream>>>(W1, B1h, B1l);
    convert_B<HID><<<HID * 64 / 256, 256, 0, stream>>>(W2, B2h, B2l);

    int gblocks = (n + 63) / 64;

    // layer 1: aggregate x (128 features), then MFMA GEMM (+b1, relu)
    aggregate<2><<<(n + 3) / 4, 256, 0, stream>>>(x, rowptr, ssrc, dinv, aggx, n);
    gemm_mfma<IN_DIM, false><<<gblocks, 256, 0, stream>>>(aggx, B1h, B1l, b1, h1,
                                                          nullptr, nullptr, nullptr, n);

    // layer 2: aggregate h1 (256 features), then MFMA GEMM (+b2, relu) fused with
    // final 256->2 projection
    aggregate<4><<<(n + 3) / 4, 256, 0, stream>>>(h1, rowptr, ssrc, dinv, aggh, n);
    gemm_mfma<HID, true><<<gblocks, 256, 0, stream>>>(aggh, B2h, B2l, b2, nullptr,
                                                      Wl, bl, out, n);
}

// Round 3
// 425.704 us; speedup vs baseline: 1.2419x; 1.0342x over previous
//
#include <hip/hip_runtime.h>
#include <hip/hip_bf16.h>

constexpr int IN_DIM = 128;
constexpr int HID    = 256;

typedef short  bf16x8 __attribute__((ext_vector_type(8)));
typedef ushort u16x8  __attribute__((ext_vector_type(8)));
typedef float  f32x4  __attribute__((ext_vector_type(4)));

__device__ inline ushort bf16_rn(float x) {
    uint u = __float_as_uint(x);
    uint r = u + 0x7FFFu + ((u >> 16) & 1u);
    return (ushort)(r >> 16);
}
__device__ inline void split_bf16(float x, ushort& hi, ushort& lo) {
    ushort h = bf16_rn(x);
    float hf = __uint_as_float(((uint)h) << 16);
    hi = h;
    lo = bf16_rn(x - hf);
}

// ---------------- setup kernels ----------------

__global__ void zero_int2(int* __restrict__ a, int* __restrict__ b, int n) {
    int i = blockIdx.x * blockDim.x + threadIdx.x;
    if (i < n) { a[i] = 0; b[i] = 0; }
}

__global__ void count_deg(const int* __restrict__ dst, int* __restrict__ deg, int e) {
    int i = blockIdx.x * blockDim.x + threadIdx.x;
    if (i < e) atomicAdd(&deg[dst[i]], 1);
}

__global__ void compute_dinv(const int* __restrict__ deg, float* __restrict__ dinv, int n) {
    int i = blockIdx.x * blockDim.x + threadIdx.x;
    if (i < n) dinv[i] = rsqrtf((float)deg[i] + 1.0f);
}

__global__ __launch_bounds__(1024) void scan_deg(const int* __restrict__ deg,
                                                 int* __restrict__ rowptr, int n) {
    __shared__ int sums[1024];
    int t = threadIdx.x;
    int chunk = (n + 1023) >> 10;
    int start = t * chunk;
    int end   = min(start + chunk, n);
    int s = 0;
    for (int i = start; i < end; i++) s += deg[i];
    sums[t] = s;
    __syncthreads();
    for (int off = 1; off < 1024; off <<= 1) {
        int v = sums[t];
        int w = (t >= off) ? sums[t - off] : 0;
        __syncthreads();
        sums[t] = v + w;
        __syncthreads();
    }
    int base = (t > 0) ? sums[t - 1] : 0;
    for (int i = start; i < end; i++) { rowptr[i] = base; base += deg[i]; }
    if (t == 0) rowptr[n] = sums[1023];
}

// also writes per-edge norm weight so aggregate never touches dinv randomly
__global__ void scatter_edges(const int* __restrict__ src, const int* __restrict__ dst,
                              const int* __restrict__ rowptr, int* __restrict__ cursor,
                              const float* __restrict__ dinv,
                              int* __restrict__ ssrc, float* __restrict__ ewt, int e) {
    int i = blockIdx.x * blockDim.x + threadIdx.x;
    if (i < e) {
        int d = dst[i];
        int s = src[i];
        int p = atomicAdd(&cursor[d], 1);
        int idx = rowptr[d] + p;
        ssrc[idx] = s;
        ewt[idx]  = dinv[s] * dinv[d];
    }
}

// ---------------- weight preconvert: B[K][256] fp32 -> hi/lo bf16 panels ----
template <int K>
__global__ void convert_B(const float* __restrict__ B, ushort* __restrict__ Bh,
                          ushort* __restrict__ Bl) {
    int id = blockIdx.x * 256 + threadIdx.x;
    if (id >= K * 64) return;
    int k  = id >> 6;
    int n4 = (id & 63) * 4;
    float4 v = *(const float4*)(B + (size_t)k * 256 + n4);
    size_t base = (size_t)(k >> 5) * (256 * 32) + (k & 31);
    float vv[4] = {v.x, v.y, v.z, v.w};
#pragma unroll
    for (int c = 0; c < 4; c++) {
        ushort h, l;
        split_bf16(vv[c], h, l);
        Bh[base + (size_t)(n4 + c) * 32] = h;
        Bl[base + (size_t)(n4 + c) * 32] = l;
    }
}

// ---------------- aggregation: one wave per node, batched indices ----------
// out[i] = sum_{j in row(i)} ewt[j]*h[ssrc[j]] + dinv[i]^2 * h[i]
template <int V>  // V floats per lane; F = 64*V features
__global__ __launch_bounds__(256) void aggregate(const float* __restrict__ h,
                                                 const int* __restrict__ rowptr,
                                                 const int* __restrict__ ssrc,
                                                 const float* __restrict__ ewt,
                                                 const float* __restrict__ dinv,
                                                 float* __restrict__ out, int n) {
    int wid  = (blockIdx.x * 256 + threadIdx.x) >> 6;
    int lane = threadIdx.x & 63;
    if (wid >= n) return;
    constexpr int F = V * 64;
    float di = dinv[wid];
    float sw = di * di;
    float acc[V];
    {
        const float* row = h + (size_t)wid * F + lane * V;
        if constexpr (V == 4) {
            float4 v = *(const float4*)row;
            acc[0] = v.x * sw; acc[1] = v.y * sw; acc[2] = v.z * sw; acc[3] = v.w * sw;
        } else {
            float2 v = *(const float2*)row;
            acc[0] = v.x * sw; acc[1] = v.y * sw;
        }
    }
    int beg = rowptr[wid], fin = rowptr[wid + 1];
    for (int b = beg; b < fin; b += 64) {
        int cnt = fin - b;
        if (cnt > 64) cnt = 64;
        // one coalesced load of up to 64 (index, weight) pairs
        int   sv = (lane < cnt) ? ssrc[b + lane] : 0;
        float wv = (lane < cnt) ? ewt[b + lane]  : 0.f;
#pragma unroll 2
        for (int t = 0; t < cnt; t++) {
            int   s = __shfl(sv, t);
            float w = __shfl(wv, t);
            const float* r = h + (size_t)s * F + lane * V;
            if constexpr (V == 4) {
                float4 v = *(const float4*)r;
                acc[0] += v.x * w; acc[1] += v.y * w; acc[2] += v.z * w; acc[3] += v.w * w;
            } else {
                float2 v = *(const float2*)r;
                acc[0] += v.x * w; acc[1] += v.y * w;
            }
        }
    }
    float* o = out + (size_t)wid * F + lane * V;
    if constexpr (V == 4) *(float4*)o = make_float4(acc[0], acc[1], acc[2], acc[3]);
    else                  *(float2*)o = make_float2(acc[0], acc[1]);
}

// ---------------- MFMA split-bf16 GEMM ----------------
// C[M,256] = relu(A[M,K] @ B[K,256] + bias); optionally fused out = C @ Wl + bl
template <int K, bool FUSE_FINAL>
__global__ __launch_bounds__(256, 3) void gemm_mfma(const float* __restrict__ A,
                                                    const ushort* __restrict__ Bh,
                                                    const ushort* __restrict__ Bl,
                                                    const float* __restrict__ bias,
                                                    float* __restrict__ C,
                                                    const float* __restrict__ Wl,
                                                    const float* __restrict__ bl,
                                                    float* __restrict__ out, int M) {
    __shared__ ushort Ah[64][40], Al[64][40];
    __shared__ ushort Bsh[256][40], Bsl[256][40];
    __shared__ float part[4][64][2];

    int tid  = threadIdx.x;
    int w    = tid >> 6;
    int lane = tid & 63;
    int l15  = lane & 15;
    int quad = lane >> 4;
    int row0 = blockIdx.x * 64;

    int arow = tid >> 2;
    int ak   = (tid & 3) * 8;
    int gr   = row0 + arow;
    bool arow_ok = (gr < M);
    const float* aptr = A + (size_t)gr * K + ak;

    f32x4 acc[4][4] = {};

    for (int k0 = 0; k0 < K; k0 += 32) {
        float av[8];
        if (arow_ok) {
            float4 v0 = *(const float4*)(aptr + k0);
            float4 v1 = *(const float4*)(aptr + k0 + 4);
            av[0]=v0.x; av[1]=v0.y; av[2]=v0.z; av[3]=v0.w;
            av[4]=v1.x; av[5]=v1.y; av[6]=v1.z; av[7]=v1.w;
        } else {
#pragma unroll
            for (int c = 0; c < 8; c++) av[c] = 0.f;
        }
        size_t panel = (size_t)(k0 >> 5) * (256 * 32) + (size_t)tid * 32;
        const uint4* bhsrc = (const uint4*)(Bh + panel);
        const uint4* blsrc = (const uint4*)(Bl + panel);
        uint4 bh0 = bhsrc[0], bh1 = bhsrc[1], bh2 = bhsrc[2], bh3 = bhsrc[3];
        uint4 bl0 = blsrc[0], bl1 = blsrc[1], bl2 = blsrc[2], bl3 = blsrc[3];

        __syncthreads();

        u16x8 hv, lv;
#pragma unroll
        for (int c = 0; c < 8; c++) {
            ushort h, l;
            split_bf16(av[c], h, l);
            hv[c] = h; lv[c] = l;
        }
        *(u16x8*)&Ah[arow][ak] = hv;
        *(u16x8*)&Al[arow][ak] = lv;
        {
            uint4* d0 = (uint4*)&Bsh[tid][0];
            d0[0]=bh0; d0[1]=bh1; d0[2]=bh2; d0[3]=bh3;
            uint4* d1 = (uint4*)&Bsl[tid][0];
            d1[0]=bl0; d1[1]=bl1; d1[2]=bl2; d1[3]=bl3;
        }
        __syncthreads();

        bf16x8 af_h[4], af_l[4], bf_h[4], bf_l[4];
#pragma unroll
        for (int i = 0; i < 4; i++) {
            af_h[i] = *(const bf16x8*)&Ah[i * 16 + l15][quad * 8];
            af_l[i] = *(const bf16x8*)&Al[i * 16 + l15][quad * 8];
        }
#pragma unroll
        for (int j = 0; j < 4; j++) {
            int n = w * 64 + j * 16 + l15;
            bf_h[j] = *(const bf16x8*)&Bsh[n][quad * 8];
            bf_l[j] = *(const bf16x8*)&Bsl[n][quad * 8];
        }
#pragma unroll
        for (int i = 0; i < 4; i++)
#pragma unroll
            for (int j = 0; j < 4; j++) {
                acc[i][j] = __builtin_amdgcn_mfma_f32_16x16x32_bf16(af_h[i], bf_h[j], acc[i][j], 0, 0, 0);
                acc[i][j] = __builtin_amdgcn_mfma_f32_16x16x32_bf16(af_h[i], bf_l[j], acc[i][j], 0, 0, 0);
                acc[i][j] = __builtin_amdgcn_mfma_f32_16x16x32_bf16(af_l[i], bf_h[j], acc[i][j], 0, 0, 0);
            }
    }

    float bj[4];
#pragma unroll
    for (int j = 0; j < 4; j++) bj[j] = bias[w * 64 + j * 16 + l15];

    if constexpr (!FUSE_FINAL) {
#pragma unroll
        for (int i = 0; i < 4; i++)
#pragma unroll
            for (int reg = 0; reg < 4; reg++) {
                int r = row0 + i * 16 + quad * 4 + reg;
                if (r < M) {
                    float* cp = C + (size_t)r * 256 + w * 64 + l15;
#pragma unroll
                    for (int j = 0; j < 4; j++)
                        cp[j * 16] = fmaxf(acc[i][j][reg] + bj[j], 0.f);
                }
            }
    } else {
        float wl0[4], wl1[4];
#pragma unroll
        for (int j = 0; j < 4; j++) {
            int cj = w * 64 + j * 16 + l15;
            float2 wv = *(const float2*)(Wl + cj * 2);
            wl0[j] = wv.x; wl1[j] = wv.y;
        }
#pragma unroll
        for (int i = 0; i < 4; i++)
#pragma unroll
            for (int reg = 0; reg < 4; reg++) {
                float s0 = 0.f, s1 = 0.f;
#pragma unroll
                for (int j = 0; j < 4; j++) {
                    float v = fmaxf(acc[i][j][reg] + bj[j], 0.f);
                    s0 += v * wl0[j];
                    s1 += v * wl1[j];
                }
#pragma unroll
                for (int off = 1; off < 16; off <<= 1) {
                    s0 += __shfl_xor(s0, off);
                    s1 += __shfl_xor(s1, off);
                }
                if (l15 == 0) {
                    int r = i * 16 + quad * 4 + reg;
                    part[w][r][0] = s0;
                    part[w][r][1] = s1;
                }
            }
        __syncthreads();
        if (tid < 128) {
            int r = tid >> 1, o = tid & 1;
            int grr = row0 + r;
            if (grr < M) {
                float s = part[0][r][o] + part[1][r][o] + part[2][r][o] + part[3][r][o] + bl[o];
                out[(size_t)grr * 2 + o] = s;
            }
        }
    }
}

// ---------------- launch ----------------

extern "C" void kernel_launch(void* const* d_in, const int* in_sizes, int n_in,
                              void* d_out, int out_size, void* d_ws, size_t ws_size,
                              hipStream_t stream) {
    const float* x  = (const float*)d_in[0];
    const int*   ei = (const int*)d_in[1];
    const float* W1 = (const float*)d_in[2];
    const float* b1 = (const float*)d_in[3];
    const float* W2 = (const float*)d_in[4];
    const float* b2 = (const float*)d_in[5];
    const float* Wl = (const float*)d_in[6];
    const float* bl = (const float*)d_in[7];
    float* out = (float*)d_out;

    int n = in_sizes[0] / IN_DIM;  // 50000
    int e = in_sizes[1] / 2;       // 600000
    const int* src = ei;
    const int* dst = ei + e;

    char* ws = (char*)d_ws;
    size_t off = 0;
    auto alloc = [&](size_t bytes) -> void* {
        void* p = ws + off;
        off += (bytes + 255) & ~(size_t)255;
        return p;
    };
    int*    deg    = (int*)alloc((size_t)n * 4);
    int*    cursor = (int*)alloc((size_t)n * 4);
    float*  dinv   = (float*)alloc((size_t)n * 4);
    int*    rowptr = (int*)alloc((size_t)(n + 1) * 4);
    int*    ssrc   = (int*)alloc((size_t)e * 4);
    float*  ewt    = (float*)alloc((size_t)e * 4);
    float*  aggx   = (float*)alloc((size_t)n * IN_DIM * 4);
    float*  h1     = (float*)alloc((size_t)n * HID * 4);
    float*  aggh   = (float*)alloc((size_t)n * HID * 4);
    ushort* B1h    = (ushort*)alloc((size_t)IN_DIM * 256 * 2);
    ushort* B1l    = (ushort*)alloc((size_t)IN_DIM * 256 * 2);
    ushort* B2h    = (ushort*)alloc((size_t)HID * 256 * 2);
    ushort* B2l    = (ushort*)alloc((size_t)HID * 256 * 2);

    int nb = (n + 255) / 256;
    int eb = (e + 255) / 256;

    zero_int2<<<nb, 256, 0, stream>>>(deg, cursor, n);
    count_deg<<<eb, 256, 0, stream>>>(dst, deg, e);
    compute_dinv<<<nb, 256, 0, stream>>>(deg, dinv, n);
    scan_deg<<<1, 1024, 0, stream>>>(deg, rowptr, n);
    scatter_edges<<<eb, 256, 0, stream>>>(src, dst, rowptr, cursor, dinv, ssrc, ewt, e);

    convert_B<IN_DIM><<<IN_DIM * 64 / 256, 256, 0, stream>>>(W1, B1h, B1l);
    convert_B<HID><<<HID * 64 / 256, 256, 0, stream>>>(W2, B2h, B2l);

    int gblocks = (n + 63) / 64;

    // layer 1: aggregate x (128 features), then MFMA GEMM (+b1, relu)
    aggregate<2><<<(n + 3) / 4, 256, 0, stream>>>(x, rowptr, ssrc, ewt, dinv, aggx, n);
    gemm_mfma<IN_DIM, false><<<gblocks, 256, 0, stream>>>(aggx, B1h, B1l, b1, h1,
                                                          nullptr, nullptr, nullptr, n);

    // layer 2: aggregate h1 (256 features), then MFMA GEMM (+b2, relu) + final proj
    aggregate<4><<<(n + 3) / 4, 256, 0, stream>>>(h1, rowptr, ssrc, ewt, dinv, aggh, n);
    gemm_mfma<HID, true><<<gblocks, 256, 0, stream>>>(aggh, B2h, B2l, b2, nullptr,
                                                      Wl, bl, out, n);
}

// Round 4
// 382.931 us; speedup vs baseline: 1.3806x; 1.1117x over previous
//
#include <hip/hip_runtime.h>
#include <hip/hip_bf16.h>
#include <hip/hip_fp16.h>

constexpr int IN_DIM = 128;
constexpr int HID    = 256;

typedef short  bf16x8 __attribute__((ext_vector_type(8)));
typedef ushort u16x8  __attribute__((ext_vector_type(8)));
typedef float  f32x4  __attribute__((ext_vector_type(4)));

__device__ inline ushort bf16_rn(float x) {
    uint u = __float_as_uint(x);
    uint r = u + 0x7FFFu + ((u >> 16) & 1u);
    return (ushort)(r >> 16);
}
__device__ inline void split_bf16(float x, ushort& hi, ushort& lo) {
    ushort h = bf16_rn(x);
    float hf = __uint_as_float(((uint)h) << 16);
    hi = h;
    lo = bf16_rn(x - hf);
}

// ---------------- setup kernels ----------------

__global__ void zero_int2(int* __restrict__ a, int* __restrict__ b, int n) {
    int i = blockIdx.x * blockDim.x + threadIdx.x;
    if (i < n) { a[i] = 0; b[i] = 0; }
}

__global__ void count_deg(const int* __restrict__ dst, int* __restrict__ deg, int e) {
    int i = blockIdx.x * blockDim.x + threadIdx.x;
    if (i < e) atomicAdd(&deg[dst[i]], 1);
}

__global__ void compute_dinv(const int* __restrict__ deg, float* __restrict__ dinv, int n) {
    int i = blockIdx.x * blockDim.x + threadIdx.x;
    if (i < n) dinv[i] = rsqrtf((float)deg[i] + 1.0f);
}

__global__ __launch_bounds__(1024) void scan_deg(const int* __restrict__ deg,
                                                 int* __restrict__ rowptr, int n) {
    __shared__ int sums[1024];
    int t = threadIdx.x;
    int chunk = (n + 1023) >> 10;
    int start = t * chunk;
    int end   = min(start + chunk, n);
    int s = 0;
    for (int i = start; i < end; i++) s += deg[i];
    sums[t] = s;
    __syncthreads();
    for (int off = 1; off < 1024; off <<= 1) {
        int v = sums[t];
        int w = (t >= off) ? sums[t - off] : 0;
        __syncthreads();
        sums[t] = v + w;
        __syncthreads();
    }
    int base = (t > 0) ? sums[t - 1] : 0;
    for (int i = start; i < end; i++) { rowptr[i] = base; base += deg[i]; }
    if (t == 0) rowptr[n] = sums[1023];
}

__global__ void scatter_edges(const int* __restrict__ src, const int* __restrict__ dst,
                              const int* __restrict__ rowptr, int* __restrict__ cursor,
                              const float* __restrict__ dinv,
                              int* __restrict__ ssrc, float* __restrict__ ewt, int e) {
    int i = blockIdx.x * blockDim.x + threadIdx.x;
    if (i < e) {
        int d = dst[i];
        int s = src[i];
        int p = atomicAdd(&cursor[d], 1);
        int idx = rowptr[d] + p;
        ssrc[idx] = s;
        ewt[idx]  = dinv[s] * dinv[d];
    }
}

// x fp32 -> fp16 (one float4 -> 4 halves per thread)
__global__ void convert_x_f16(const float* __restrict__ x, ushort* __restrict__ xh,
                              int total4) {
    int i = blockIdx.x * blockDim.x + threadIdx.x;
    if (i >= total4) return;
    float4 v = *(const float4*)(x + (size_t)i * 4);
    ushort4 o;
    o.x = __half_as_ushort(__float2half(v.x));
    o.y = __half_as_ushort(__float2half(v.y));
    o.z = __half_as_ushort(__float2half(v.z));
    o.w = __half_as_ushort(__float2half(v.w));
    *(ushort4*)(xh + (size_t)i * 4) = o;
}

// ---------------- weight preconvert: B[K][256] fp32 -> hi/lo bf16 panels ----
template <int K>
__global__ void convert_B(const float* __restrict__ B, ushort* __restrict__ Bh,
                          ushort* __restrict__ Bl) {
    int id = blockIdx.x * 256 + threadIdx.x;
    if (id >= K * 64) return;
    int k  = id >> 6;
    int n4 = (id & 63) * 4;
    float4 v = *(const float4*)(B + (size_t)k * 256 + n4);
    size_t base = (size_t)(k >> 5) * (256 * 32) + (k & 31);
    float vv[4] = {v.x, v.y, v.z, v.w};
#pragma unroll
    for (int c = 0; c < 4; c++) {
        ushort h, l;
        split_bf16(vv[c], h, l);
        Bh[base + (size_t)(n4 + c) * 32] = h;
        Bl[base + (size_t)(n4 + c) * 32] = l;
    }
}

// ---------------- aggregation: one wave per node, fp16 gather ----------
// out[i] = sum_{j in row(i)} ewt[j]*h[ssrc[j]] + dinv[i]^2 * h[i]   (fp32 accum)
template <int F>  // F halves per row: 128 or 256
__global__ __launch_bounds__(256) void aggregate_h(const ushort* __restrict__ h,
                                                   const int* __restrict__ rowptr,
                                                   const int* __restrict__ ssrc,
                                                   const float* __restrict__ ewt,
                                                   const float* __restrict__ dinv,
                                                   float* __restrict__ out, int n) {
    constexpr int VH = F / 64;  // halves per lane: 2 or 4
    int wid  = (blockIdx.x * 256 + threadIdx.x) >> 6;
    int lane = threadIdx.x & 63;
    if (wid >= n) return;
    float di = dinv[wid];
    float sw = di * di;
    float acc[VH];
    {
        const ushort* row = h + (size_t)wid * F + lane * VH;
        if constexpr (VH == 4) {
            uint2 u = *(const uint2*)row;
            float2 fa = __half22float2(*(__half2*)&u.x);
            float2 fb = __half22float2(*(__half2*)&u.y);
            acc[0] = fa.x * sw; acc[1] = fa.y * sw; acc[2] = fb.x * sw; acc[3] = fb.y * sw;
        } else {
            uint u = *(const uint*)row;
            float2 fa = __half22float2(*(__half2*)&u);
            acc[0] = fa.x * sw; acc[1] = fa.y * sw;
        }
    }
    int beg = rowptr[wid], fin = rowptr[wid + 1];
    for (int b = beg; b < fin; b += 64) {
        int cnt = fin - b;
        if (cnt > 64) cnt = 64;
        int   sv = (lane < cnt) ? ssrc[b + lane] : 0;
        float wv = (lane < cnt) ? ewt[b + lane]  : 0.f;
#pragma unroll 2
        for (int t = 0; t < cnt; t++) {
            int   s = __shfl(sv, t);
            float w = __shfl(wv, t);
            const ushort* r = h + (size_t)s * F + lane * VH;
            if constexpr (VH == 4) {
                uint2 u = *(const uint2*)r;
                float2 fa = __half22float2(*(__half2*)&u.x);
                float2 fb = __half22float2(*(__half2*)&u.y);
                acc[0] += fa.x * w; acc[1] += fa.y * w;
                acc[2] += fb.x * w; acc[3] += fb.y * w;
            } else {
                uint u = *(const uint*)r;
                float2 fa = __half22float2(*(__half2*)&u);
                acc[0] += fa.x * w; acc[1] += fa.y * w;
            }
        }
    }
    float* o = out + (size_t)wid * F + lane * VH;
    if constexpr (VH == 4) *(float4*)o = make_float4(acc[0], acc[1], acc[2], acc[3]);
    else                   *(float2*)o = make_float2(acc[0], acc[1]);
}

// ---------------- MFMA split-bf16 GEMM ----------------
// MODE 1: C16[M,256] = fp16(relu(A@B + bias))
// MODE 2: out[M,2] = relu(A@B + bias) @ Wl + bl   (C not materialized)
template <int K, int MODE>
__global__ __launch_bounds__(256, 3) void gemm_mfma(const float* __restrict__ A,
                                                    const ushort* __restrict__ Bh,
                                                    const ushort* __restrict__ Bl,
                                                    const float* __restrict__ bias,
                                                    ushort* __restrict__ C16,
                                                    const float* __restrict__ Wl,
                                                    const float* __restrict__ bl,
                                                    float* __restrict__ out, int M) {
    __shared__ ushort Ah[64][40], Al[64][40];
    __shared__ ushort Bsh[256][40], Bsl[256][40];
    __shared__ float part[4][64][2];

    int tid  = threadIdx.x;
    int w    = tid >> 6;
    int lane = tid & 63;
    int l15  = lane & 15;
    int quad = lane >> 4;
    int row0 = blockIdx.x * 64;

    int arow = tid >> 2;
    int ak   = (tid & 3) * 8;
    int gr   = row0 + arow;
    bool arow_ok = (gr < M);
    const float* aptr = A + (size_t)gr * K + ak;

    f32x4 acc[4][4] = {};

    for (int k0 = 0; k0 < K; k0 += 32) {
        float av[8];
        if (arow_ok) {
            float4 v0 = *(const float4*)(aptr + k0);
            float4 v1 = *(const float4*)(aptr + k0 + 4);
            av[0]=v0.x; av[1]=v0.y; av[2]=v0.z; av[3]=v0.w;
            av[4]=v1.x; av[5]=v1.y; av[6]=v1.z; av[7]=v1.w;
        } else {
#pragma unroll
            for (int c = 0; c < 8; c++) av[c] = 0.f;
        }
        size_t panel = (size_t)(k0 >> 5) * (256 * 32) + (size_t)tid * 32;
        const uint4* bhsrc = (const uint4*)(Bh + panel);
        const uint4* blsrc = (const uint4*)(Bl + panel);
        uint4 bh0 = bhsrc[0], bh1 = bhsrc[1], bh2 = bhsrc[2], bh3 = bhsrc[3];
        uint4 bl0 = blsrc[0], bl1 = blsrc[1], bl2 = blsrc[2], bl3 = blsrc[3];

        __syncthreads();

        u16x8 hv, lv;
#pragma unroll
        for (int c = 0; c < 8; c++) {
            ushort h, l;
            split_bf16(av[c], h, l);
            hv[c] = h; lv[c] = l;
        }
        *(u16x8*)&Ah[arow][ak] = hv;
        *(u16x8*)&Al[arow][ak] = lv;
        {
            uint4* d0 = (uint4*)&Bsh[tid][0];
            d0[0]=bh0; d0[1]=bh1; d0[2]=bh2; d0[3]=bh3;
            uint4* d1 = (uint4*)&Bsl[tid][0];
            d1[0]=bl0; d1[1]=bl1; d1[2]=bl2; d1[3]=bl3;
        }
        __syncthreads();

        bf16x8 af_h[4], af_l[4], bf_h[4], bf_l[4];
#pragma unroll
        for (int i = 0; i < 4; i++) {
            af_h[i] = *(const bf16x8*)&Ah[i * 16 + l15][quad * 8];
            af_l[i] = *(const bf16x8*)&Al[i * 16 + l15][quad * 8];
        }
#pragma unroll
        for (int j = 0; j < 4; j++) {
            int n = w * 64 + j * 16 + l15;
            bf_h[j] = *(const bf16x8*)&Bsh[n][quad * 8];
            bf_l[j] = *(const bf16x8*)&Bsl[n][quad * 8];
        }
#pragma unroll
        for (int i = 0; i < 4; i++)
#pragma unroll
            for (int j = 0; j < 4; j++) {
                acc[i][j] = __builtin_amdgcn_mfma_f32_16x16x32_bf16(af_h[i], bf_h[j], acc[i][j], 0, 0, 0);
                acc[i][j] = __builtin_amdgcn_mfma_f32_16x16x32_bf16(af_h[i], bf_l[j], acc[i][j], 0, 0, 0);
                acc[i][j] = __builtin_amdgcn_mfma_f32_16x16x32_bf16(af_l[i], bf_h[j], acc[i][j], 0, 0, 0);
            }
    }

    float bj[4];
#pragma unroll
    for (int j = 0; j < 4; j++) bj[j] = bias[w * 64 + j * 16 + l15];

    if constexpr (MODE == 1) {
#pragma unroll
        for (int i = 0; i < 4; i++)
#pragma unroll
            for (int reg = 0; reg < 4; reg++) {
                int r = row0 + i * 16 + quad * 4 + reg;
                if (r < M) {
                    ushort* cp = C16 + (size_t)r * 256 + w * 64 + l15;
#pragma unroll
                    for (int j = 0; j < 4; j++) {
                        float v = fmaxf(acc[i][j][reg] + bj[j], 0.f);
                        cp[j * 16] = __half_as_ushort(__float2half(v));
                    }
                }
            }
    } else {
        float wl0[4], wl1[4];
#pragma unroll
        for (int j = 0; j < 4; j++) {
            int cj = w * 64 + j * 16 + l15;
            float2 wv = *(const float2*)(Wl + cj * 2);
            wl0[j] = wv.x; wl1[j] = wv.y;
        }
#pragma unroll
        for (int i = 0; i < 4; i++)
#pragma unroll
            for (int reg = 0; reg < 4; reg++) {
                float s0 = 0.f, s1 = 0.f;
#pragma unroll
                for (int j = 0; j < 4; j++) {
                    float v = fmaxf(acc[i][j][reg] + bj[j], 0.f);
                    s0 += v * wl0[j];
                    s1 += v * wl1[j];
                }
#pragma unroll
                for (int off = 1; off < 16; off <<= 1) {
                    s0 += __shfl_xor(s0, off);
                    s1 += __shfl_xor(s1, off);
                }
                if (l15 == 0) {
                    int r = i * 16 + quad * 4 + reg;
                    part[w][r][0] = s0;
                    part[w][r][1] = s1;
                }
            }
        __syncthreads();
        if (tid < 128) {
            int r = tid >> 1, o = tid & 1;
            int grr = row0 + r;
            if (grr < M) {
                float s = part[0][r][o] + part[1][r][o] + part[2][r][o] + part[3][r][o] + bl[o];
                out[(size_t)grr * 2 + o] = s;
            }
        }
    }
}

// ---------------- launch ----------------

extern "C" void kernel_launch(void* const* d_in, const int* in_sizes, int n_in,
                              void* d_out, int out_size, void* d_ws, size_t ws_size,
                              hipStream_t stream) {
    const float* x  = (const float*)d_in[0];
    const int*   ei = (const int*)d_in[1];
    const float* W1 = (const float*)d_in[2];
    const float* b1 = (const float*)d_in[3];
    const float* W2 = (const float*)d_in[4];
    const float* b2 = (const float*)d_in[5];
    const float* Wl = (const float*)d_in[6];
    const float* bl = (const float*)d_in[7];
    float* out = (float*)d_out;

    int n = in_sizes[0] / IN_DIM;  // 50000
    int e = in_sizes[1] / 2;       // 600000
    const int* src = ei;
    const int* dst = ei + e;

    char* ws = (char*)d_ws;
    size_t off = 0;
    auto alloc = [&](size_t bytes) -> void* {
        void* p = ws + off;
        off += (bytes + 255) & ~(size_t)255;
        return p;
    };
    int*    deg    = (int*)alloc((size_t)n * 4);
    int*    cursor = (int*)alloc((size_t)n * 4);
    float*  dinv   = (float*)alloc((size_t)n * 4);
    int*    rowptr = (int*)alloc((size_t)(n + 1) * 4);
    int*    ssrc   = (int*)alloc((size_t)e * 4);
    float*  ewt    = (float*)alloc((size_t)e * 4);
    ushort* xh     = (ushort*)alloc((size_t)n * IN_DIM * 2);   // fp16 x
    float*  aggx   = (float*)alloc((size_t)n * IN_DIM * 4);
    ushort* h1     = (ushort*)alloc((size_t)n * HID * 2);      // fp16 h1
    float*  aggh   = (float*)alloc((size_t)n * HID * 4);
    ushort* B1h    = (ushort*)alloc((size_t)IN_DIM * 256 * 2);
    ushort* B1l    = (ushort*)alloc((size_t)IN_DIM * 256 * 2);
    ushort* B2h    = (ushort*)alloc((size_t)HID * 256 * 2);
    ushort* B2l    = (ushort*)alloc((size_t)HID * 256 * 2);

    int nb = (n + 255) / 256;
    int eb = (e + 255) / 256;

    zero_int2<<<nb, 256, 0, stream>>>(deg, cursor, n);
    count_deg<<<eb, 256, 0, stream>>>(dst, deg, e);
    compute_dinv<<<nb, 256, 0, stream>>>(deg, dinv, n);
    scan_deg<<<1, 1024, 0, stream>>>(deg, rowptr, n);
    scatter_edges<<<eb, 256, 0, stream>>>(src, dst, rowptr, cursor, dinv, ssrc, ewt, e);

    int total4 = n * IN_DIM / 4;
    convert_x_f16<<<(total4 + 255) / 256, 256, 0, stream>>>(x, xh, total4);
    convert_B<IN_DIM><<<IN_DIM * 64 / 256, 256, 0, stream>>>(W1, B1h, B1l);
    convert_B<HID><<<HID * 64 / 256, 256, 0, stream>>>(W2, B2h, B2l);

    int gblocks = (n + 63) / 64;

    // layer 1: aggregate fp16 x (128 features), then MFMA GEMM -> fp16 h1
    aggregate_h<IN_DIM><<<(n + 3) / 4, 256, 0, stream>>>(xh, rowptr, ssrc, ewt, dinv, aggx, n);
    gemm_mfma<IN_DIM, 1><<<gblocks, 256, 0, stream>>>(aggx, B1h, B1l, b1, h1,
                                                      nullptr, nullptr, nullptr, n);

    // layer 2: aggregate fp16 h1 (256 features), then MFMA GEMM + final proj
    aggregate_h<HID><<<(n + 3) / 4, 256, 0, stream>>>(h1, rowptr, ssrc, ewt, dinv, aggh, n);
    gemm_mfma<HID, 2><<<gblocks, 256, 0, stream>>>(aggh, B2h, B2l, b2, nullptr,
                                                   Wl, bl, out, n);
}

// Round 5
// 317.579 us; speedup vs baseline: 1.6647x; 1.2058x over previous
//
#include <hip/hip_runtime.h>
#include <hip/hip_bf16.h>
#include <hip/hip_fp16.h>

constexpr int IN_DIM = 128;
constexpr int HID    = 256;

typedef short  bf16x8 __attribute__((ext_vector_type(8)));
typedef ushort u16x8  __attribute__((ext_vector_type(8)));
typedef float  f32x4  __attribute__((ext_vector_type(4)));

__device__ inline ushort bf16_rn(float x) {
    uint u = __float_as_uint(x);
    uint r = u + 0x7FFFu + ((u >> 16) & 1u);
    return (ushort)(r >> 16);
}
__device__ inline void split_bf16(float x, ushort& hi, ushort& lo) {
    ushort h = bf16_rn(x);
    float hf = __uint_as_float(((uint)h) << 16);
    hi = h;
    lo = bf16_rn(x - hf);
}

// ---------------- setup kernels ----------------

__global__ void zero_int2(int* __restrict__ a, int* __restrict__ b, int n) {
    int i = blockIdx.x * blockDim.x + threadIdx.x;
    if (i < n) { a[i] = 0; b[i] = 0; }
}

__global__ void count_deg(const int* __restrict__ dst, int* __restrict__ deg, int e) {
    int i = blockIdx.x * blockDim.x + threadIdx.x;
    if (i < e) atomicAdd(&deg[dst[i]], 1);
}

__global__ void compute_dinv(const int* __restrict__ deg, float* __restrict__ dinv, int n) {
    int i = blockIdx.x * blockDim.x + threadIdx.x;
    if (i < n) dinv[i] = rsqrtf((float)deg[i] + 1.0f);
}

// ---- device-wide exclusive scan of deg -> rowptr, 3 phases ----
// phase 1: per-block (256 elems) exclusive scan + block total
__global__ __launch_bounds__(256) void scan_partial(const int* __restrict__ deg,
                                                    int* __restrict__ escan,
                                                    int* __restrict__ blocksum, int n) {
    __shared__ int lds[256];
    int t = threadIdx.x;
    int i = blockIdx.x * 256 + t;
    int v = (i < n) ? deg[i] : 0;
    lds[t] = v;
    __syncthreads();
    for (int off = 1; off < 256; off <<= 1) {
        int a = lds[t];
        int w = (t >= off) ? lds[t - off] : 0;
        __syncthreads();
        lds[t] = a + w;
        __syncthreads();
    }
    if (i < n) escan[i] = lds[t] - v;
    if (t == 255) blocksum[blockIdx.x] = lds[255];
}

// phase 2: single block scans the block totals (nb <= 256); writes rowptr[n]
__global__ __launch_bounds__(256) void scan_blocksums(const int* __restrict__ blocksum,
                                                      int* __restrict__ blockoff,
                                                      int nb, int* __restrict__ rowptr_n) {
    __shared__ int lds[256];
    int t = threadIdx.x;
    int v = (t < nb) ? blocksum[t] : 0;
    lds[t] = v;
    __syncthreads();
    for (int off = 1; off < 256; off <<= 1) {
        int a = lds[t];
        int w = (t >= off) ? lds[t - off] : 0;
        __syncthreads();
        lds[t] = a + w;
        __syncthreads();
    }
    if (t < nb) blockoff[t] = lds[t] - v;
    if (t == 255) *rowptr_n = lds[255];
}

// phase 3: add block offsets
__global__ void scan_finalize(const int* __restrict__ escan, const int* __restrict__ blockoff,
                              int* __restrict__ rowptr, int n) {
    int i = blockIdx.x * 256 + threadIdx.x;
    if (i < n) rowptr[i] = escan[i] + blockoff[blockIdx.x];
}

__global__ void scatter_edges(const int* __restrict__ src, const int* __restrict__ dst,
                              const int* __restrict__ rowptr, int* __restrict__ cursor,
                              const float* __restrict__ dinv,
                              int* __restrict__ ssrc, float* __restrict__ ewt, int e) {
    int i = blockIdx.x * blockDim.x + threadIdx.x;
    if (i < e) {
        int d = dst[i];
        int s = src[i];
        int p = atomicAdd(&cursor[d], 1);
        int idx = rowptr[d] + p;
        ssrc[idx] = s;
        ewt[idx]  = dinv[s] * dinv[d];
    }
}

// x fp32 -> fp16
__global__ void convert_x_f16(const float* __restrict__ x, ushort* __restrict__ xh,
                              int total4) {
    int i = blockIdx.x * blockDim.x + threadIdx.x;
    if (i >= total4) return;
    float4 v = *(const float4*)(x + (size_t)i * 4);
    ushort4 o;
    o.x = __half_as_ushort(__float2half(v.x));
    o.y = __half_as_ushort(__float2half(v.y));
    o.z = __half_as_ushort(__float2half(v.z));
    o.w = __half_as_ushort(__float2half(v.w));
    *(ushort4*)(xh + (size_t)i * 4) = o;
}

// ---------------- weight preconvert: B[K][256] fp32 -> hi/lo bf16 panels ----
template <int K>
__global__ void convert_B(const float* __restrict__ B, ushort* __restrict__ Bh,
                          ushort* __restrict__ Bl) {
    int id = blockIdx.x * 256 + threadIdx.x;
    if (id >= K * 64) return;
    int k  = id >> 6;
    int n4 = (id & 63) * 4;
    float4 v = *(const float4*)(B + (size_t)k * 256 + n4);
    size_t base = (size_t)(k >> 5) * (256 * 32) + (k & 31);
    float vv[4] = {v.x, v.y, v.z, v.w};
#pragma unroll
    for (int c = 0; c < 4; c++) {
        ushort h, l;
        split_bf16(vv[c], h, l);
        Bh[base + (size_t)(n4 + c) * 32] = h;
        Bl[base + (size_t)(n4 + c) * 32] = l;
    }
}

// ---------------- aggregation: one wave per node, fp16 gather ----------
template <int F>  // F halves per row: 128 or 256
__global__ __launch_bounds__(256) void aggregate_h(const ushort* __restrict__ h,
                                                   const int* __restrict__ rowptr,
                                                   const int* __restrict__ ssrc,
                                                   const float* __restrict__ ewt,
                                                   const float* __restrict__ dinv,
                                                   float* __restrict__ out, int n) {
    constexpr int VH = F / 64;  // halves per lane: 2 or 4
    int wid  = (blockIdx.x * 256 + threadIdx.x) >> 6;
    int lane = threadIdx.x & 63;
    if (wid >= n) return;
    float di = dinv[wid];
    float sw = di * di;
    float acc[VH];
    {
        const ushort* row = h + (size_t)wid * F + lane * VH;
        if constexpr (VH == 4) {
            uint2 u = *(const uint2*)row;
            float2 fa = __half22float2(*(__half2*)&u.x);
            float2 fb = __half22float2(*(__half2*)&u.y);
            acc[0] = fa.x * sw; acc[1] = fa.y * sw; acc[2] = fb.x * sw; acc[3] = fb.y * sw;
        } else {
            uint u = *(const uint*)row;
            float2 fa = __half22float2(*(__half2*)&u);
            acc[0] = fa.x * sw; acc[1] = fa.y * sw;
        }
    }
    int beg = rowptr[wid], fin = rowptr[wid + 1];
    for (int b = beg; b < fin; b += 64) {
        int cnt = fin - b;
        if (cnt > 64) cnt = 64;
        int   sv = (lane < cnt) ? ssrc[b + lane] : 0;
        float wv = (lane < cnt) ? ewt[b + lane]  : 0.f;
#pragma unroll 2
        for (int t = 0; t < cnt; t++) {
            int   s = __shfl(sv, t);
            float w = __shfl(wv, t);
            const ushort* r = h + (size_t)s * F + lane * VH;
            if constexpr (VH == 4) {
                uint2 u = *(const uint2*)r;
                float2 fa = __half22float2(*(__half2*)&u.x);
                float2 fb = __half22float2(*(__half2*)&u.y);
                acc[0] += fa.x * w; acc[1] += fa.y * w;
                acc[2] += fb.x * w; acc[3] += fb.y * w;
            } else {
                uint u = *(const uint*)r;
                float2 fa = __half22float2(*(__half2*)&u);
                acc[0] += fa.x * w; acc[1] += fa.y * w;
            }
        }
    }
    float* o = out + (size_t)wid * F + lane * VH;
    if constexpr (VH == 4) *(float4*)o = make_float4(acc[0], acc[1], acc[2], acc[3]);
    else                   *(float2*)o = make_float2(acc[0], acc[1]);
}

// ---------------- MFMA split-bf16 GEMM ----------------
// MODE 1: C16[M,256] = fp16(relu(A@B + bias))
// MODE 2: out[M,2] = relu(A@B + bias) @ Wl + bl
template <int K, int MODE>
__global__ __launch_bounds__(256, 3) void gemm_mfma(const float* __restrict__ A,
                                                    const ushort* __restrict__ Bh,
                                                    const ushort* __restrict__ Bl,
                                                    const float* __restrict__ bias,
                                                    ushort* __restrict__ C16,
                                                    const float* __restrict__ Wl,
                                                    const float* __restrict__ bl,
                                                    float* __restrict__ out, int M) {
    __shared__ ushort Ah[64][40], Al[64][40];
    __shared__ ushort Bsh[256][40], Bsl[256][40];
    __shared__ float part[4][64][2];

    int tid  = threadIdx.x;
    int w    = tid >> 6;
    int lane = tid & 63;
    int l15  = lane & 15;
    int quad = lane >> 4;
    int row0 = blockIdx.x * 64;

    int arow = tid >> 2;
    int ak   = (tid & 3) * 8;
    int gr   = row0 + arow;
    bool arow_ok = (gr < M);
    const float* aptr = A + (size_t)gr * K + ak;

    f32x4 acc[4][4] = {};

    for (int k0 = 0; k0 < K; k0 += 32) {
        float av[8];
        if (arow_ok) {
            float4 v0 = *(const float4*)(aptr + k0);
            float4 v1 = *(const float4*)(aptr + k0 + 4);
            av[0]=v0.x; av[1]=v0.y; av[2]=v0.z; av[3]=v0.w;
            av[4]=v1.x; av[5]=v1.y; av[6]=v1.z; av[7]=v1.w;
        } else {
#pragma unroll
            for (int c = 0; c < 8; c++) av[c] = 0.f;
        }
        size_t panel = (size_t)(k0 >> 5) * (256 * 32) + (size_t)tid * 32;
        const uint4* bhsrc = (const uint4*)(Bh + panel);
        const uint4* blsrc = (const uint4*)(Bl + panel);
        uint4 bh0 = bhsrc[0], bh1 = bhsrc[1], bh2 = bhsrc[2], bh3 = bhsrc[3];
        uint4 bl0 = blsrc[0], bl1 = blsrc[1], bl2 = blsrc[2], bl3 = blsrc[3];

        __syncthreads();

        u16x8 hv, lv;
#pragma unroll
        for (int c = 0; c < 8; c++) {
            ushort h, l;
            split_bf16(av[c], h, l);
            hv[c] = h; lv[c] = l;
        }
        *(u16x8*)&Ah[arow][ak] = hv;
        *(u16x8*)&Al[arow][ak] = lv;
        {
            uint4* d0 = (uint4*)&Bsh[tid][0];
            d0[0]=bh0; d0[1]=bh1; d0[2]=bh2; d0[3]=bh3;
            uint4* d1 = (uint4*)&Bsl[tid][0];
            d1[0]=bl0; d1[1]=bl1; d1[2]=bl2; d1[3]=bl3;
        }
        __syncthreads();

        bf16x8 af_h[4], af_l[4], bf_h[4], bf_l[4];
#pragma unroll
        for (int i = 0; i < 4; i++) {
            af_h[i] = *(const bf16x8*)&Ah[i * 16 + l15][quad * 8];
            af_l[i] = *(const bf16x8*)&Al[i * 16 + l15][quad * 8];
        }
#pragma unroll
        for (int j = 0; j < 4; j++) {
            int nn = w * 64 + j * 16 + l15;
            bf_h[j] = *(const bf16x8*)&Bsh[nn][quad * 8];
            bf_l[j] = *(const bf16x8*)&Bsl[nn][quad * 8];
        }
#pragma unroll
        for (int i = 0; i < 4; i++)
#pragma unroll
            for (int j = 0; j < 4; j++) {
                acc[i][j] = __builtin_amdgcn_mfma_f32_16x16x32_bf16(af_h[i], bf_h[j], acc[i][j], 0, 0, 0);
                acc[i][j] = __builtin_amdgcn_mfma_f32_16x16x32_bf16(af_h[i], bf_l[j], acc[i][j], 0, 0, 0);
                acc[i][j] = __builtin_amdgcn_mfma_f32_16x16x32_bf16(af_l[i], bf_h[j], acc[i][j], 0, 0, 0);
            }
    }

    float bj[4];
#pragma unroll
    for (int j = 0; j < 4; j++) bj[j] = bias[w * 64 + j * 16 + l15];

    if constexpr (MODE == 1) {
#pragma unroll
        for (int i = 0; i < 4; i++)
#pragma unroll
            for (int reg = 0; reg < 4; reg++) {
                int r = row0 + i * 16 + quad * 4 + reg;
                if (r < M) {
                    ushort* cp = C16 + (size_t)r * 256 + w * 64 + l15;
#pragma unroll
                    for (int j = 0; j < 4; j++) {
                        float v = fmaxf(acc[i][j][reg] + bj[j], 0.f);
                        cp[j * 16] = __half_as_ushort(__float2half(v));
                    }
                }
            }
    } else {
        float wl0[4], wl1[4];
#pragma unroll
        for (int j = 0; j < 4; j++) {
            int cj = w * 64 + j * 16 + l15;
            float2 wv = *(const float2*)(Wl + cj * 2);
            wl0[j] = wv.x; wl1[j] = wv.y;
        }
#pragma unroll
        for (int i = 0; i < 4; i++)
#pragma unroll
            for (int reg = 0; reg < 4; reg++) {
                float s0 = 0.f, s1 = 0.f;
#pragma unroll
                for (int j = 0; j < 4; j++) {
                    float v = fmaxf(acc[i][j][reg] + bj[j], 0.f);
                    s0 += v * wl0[j];
                    s1 += v * wl1[j];
                }
#pragma unroll
                for (int off = 1; off < 16; off <<= 1) {
                    s0 += __shfl_xor(s0, off);
                    s1 += __shfl_xor(s1, off);
                }
                if (l15 == 0) {
                    int r = i * 16 + quad * 4 + reg;
                    part[w][r][0] = s0;
                    part[w][r][1] = s1;
                }
            }
        __syncthreads();
        if (tid < 128) {
            int r = tid >> 1, o = tid & 1;
            int grr = row0 + r;
            if (grr < M) {
                float s = part[0][r][o] + part[1][r][o] + part[2][r][o] + part[3][r][o] + bl[o];
                out[(size_t)grr * 2 + o] = s;
            }
        }
    }
}

// ---------------- launch ----------------

extern "C" void kernel_launch(void* const* d_in, const int* in_sizes, int n_in,
                              void* d_out, int out_size, void* d_ws, size_t ws_size,
                              hipStream_t stream) {
    const float* x  = (const float*)d_in[0];
    const int*   ei = (const int*)d_in[1];
    const float* W1 = (const float*)d_in[2];
    const float* b1 = (const float*)d_in[3];
    const float* W2 = (const float*)d_in[4];
    const float* b2 = (const float*)d_in[5];
    const float* Wl = (const float*)d_in[6];
    const float* bl = (const float*)d_in[7];
    float* out = (float*)d_out;

    int n = in_sizes[0] / IN_DIM;  // 50000
    int e = in_sizes[1] / 2;       // 600000
    const int* src = ei;
    const int* dst = ei + e;

    char* ws = (char*)d_ws;
    size_t off = 0;
    auto alloc = [&](size_t bytes) -> void* {
        void* p = ws + off;
        off += (bytes + 255) & ~(size_t)255;
        return p;
    };
    int*    deg    = (int*)alloc((size_t)n * 4);
    int*    cursor = (int*)alloc((size_t)n * 4);
    float*  dinv   = (float*)alloc((size_t)n * 4);
    int*    rowptr = (int*)alloc((size_t)(n + 1) * 4);
    int*    escan  = (int*)alloc((size_t)n * 4);
    int*    bsum   = (int*)alloc(256 * 4);
    int*    boff   = (int*)alloc(256 * 4);
    int*    ssrc   = (int*)alloc((size_t)e * 4);
    float*  ewt    = (float*)alloc((size_t)e * 4);
    ushort* xh     = (ushort*)alloc((size_t)n * IN_DIM * 2);
    float*  aggx   = (float*)alloc((size_t)n * IN_DIM * 4);
    ushort* h1     = (ushort*)alloc((size_t)n * HID * 2);
    float*  aggh   = (float*)alloc((size_t)n * HID * 4);
    ushort* B1h    = (ushort*)alloc((size_t)IN_DIM * 256 * 2);
    ushort* B1l    = (ushort*)alloc((size_t)IN_DIM * 256 * 2);
    ushort* B2h    = (ushort*)alloc((size_t)HID * 256 * 2);
    ushort* B2l    = (ushort*)alloc((size_t)HID * 256 * 2);

    int nb = (n + 255) / 256;   // 196 (must be <= 256)
    int eb = (e + 255) / 256;

    zero_int2<<<nb, 256, 0, stream>>>(deg, cursor, n);
    count_deg<<<eb, 256, 0, stream>>>(dst, deg, e);
    compute_dinv<<<nb, 256, 0, stream>>>(deg, dinv, n);

    scan_partial<<<nb, 256, 0, stream>>>(deg, escan, bsum, n);
    scan_blocksums<<<1, 256, 0, stream>>>(bsum, boff, nb, rowptr + n);
    scan_finalize<<<nb, 256, 0, stream>>>(escan, boff, rowptr, n);

    scatter_edges<<<eb, 256, 0, stream>>>(src, dst, rowptr, cursor, dinv, ssrc, ewt, e);

    int total4 = n * IN_DIM / 4;
    convert_x_f16<<<(total4 + 255) / 256, 256, 0, stream>>>(x, xh, total4);
    convert_B<IN_DIM><<<IN_DIM * 64 / 256, 256, 0, stream>>>(W1, B1h, B1l);
    convert_B<HID><<<HID * 64 / 256, 256, 0, stream>>>(W2, B2h, B2l);

    int gblocks = (n + 63) / 64;

    // layer 1: aggregate fp16 x (128 features), then MFMA GEMM -> fp16 h1
    aggregate_h<IN_DIM><<<(n + 3) / 4, 256, 0, stream>>>(xh, rowptr, ssrc, ewt, dinv, aggx, n);
    gemm_mfma<IN_DIM, 1><<<gblocks, 256, 0, stream>>>(aggx, B1h, B1l, b1, h1,
                                                      nullptr, nullptr, nullptr, n);

    // layer 2: aggregate fp16 h1 (256 features), then MFMA GEMM + final proj
    aggregate_h<HID><<<(n + 3) / 4, 256, 0, stream>>>(h1, rowptr, ssrc, ewt, dinv, aggh, n);
    gemm_mfma<HID, 2><<<gblocks, 256, 0, stream>>>(aggh, B2h, B2l, b2, nullptr,
                                                   Wl, bl, out, n);
}